// Round 17
// baseline (8987.944 us; speedup 1.0000x reference)
//
#include <hip/hip_runtime.h>
#include <hip/hip_bf16.h>
#include <math.h>

#define B_   128
#define HW_  224
#define P_   16
#define D_   512
#define NH_  8
#define L_   6
#define M_   2048
#define NC_  10
#define GP_  14
#define T_   197
#define TP_  224    // padded T (multiple of 32)
#define EPS_ 1e-5f
#define ZVW2_ 2048  // fused 2-head [Z0|V0|Z1|V1] output width
#define RCW_ 448    // Rcat width (2 heads x 224)

typedef __hip_bfloat16 bf16;
typedef __attribute__((ext_vector_type(8))) __bf16 bf16x8;
typedef __attribute__((ext_vector_type(4))) float  f32x4;

// async global->LDS, 16B per lane. LDS dest = wave-uniform base + lane*16.
__device__ __forceinline__ void gload16(const void* g, void* l) {
    __builtin_amdgcn_global_load_lds(
        (const __attribute__((address_space(1))) void*)g,
        (__attribute__((address_space(3))) void*)l, 16, 0, 0);
}

#define SCHED0_ __builtin_amdgcn_sched_barrier(0)

// ---------------- elementwise / prep helpers ----------------

__global__ void k_f32_to_bf16v(const float* __restrict__ in, bf16* __restrict__ out, long n8) {
    long stride = (long)gridDim.x * blockDim.x;
    for (long i = (long)blockIdx.x * blockDim.x + threadIdx.x; i < n8; i += stride) {
        float4 a = ((const float4*)in)[i * 2], b = ((const float4*)in)[i * 2 + 1];
        union { uint4 u; bf16 h[8]; } r;
        r.h[0] = __float2bfloat16(a.x); r.h[1] = __float2bfloat16(a.y);
        r.h[2] = __float2bfloat16(a.z); r.h[3] = __float2bfloat16(a.w);
        r.h[4] = __float2bfloat16(b.x); r.h[5] = __float2bfloat16(b.y);
        r.h[6] = __float2bfloat16(b.z); r.h[7] = __float2bfloat16(b.w);
        ((uint4*)out)[i] = r.u;
    }
}

// two equal-size conversions in one launch
__global__ void k_f32_to_bf16v2(const float* __restrict__ in1, bf16* __restrict__ out1,
                                const float* __restrict__ in2, bf16* __restrict__ out2, long n8) {
    long stride = (long)gridDim.x * blockDim.x;
    for (long i = (long)blockIdx.x * blockDim.x + threadIdx.x; i < n8; i += stride) {
        {
            float4 a = ((const float4*)in1)[i * 2], b = ((const float4*)in1)[i * 2 + 1];
            union { uint4 u; bf16 h[8]; } r;
            r.h[0] = __float2bfloat16(a.x); r.h[1] = __float2bfloat16(a.y);
            r.h[2] = __float2bfloat16(a.z); r.h[3] = __float2bfloat16(a.w);
            r.h[4] = __float2bfloat16(b.x); r.h[5] = __float2bfloat16(b.y);
            r.h[6] = __float2bfloat16(b.z); r.h[7] = __float2bfloat16(b.w);
            ((uint4*)out1)[i] = r.u;
        }
        {
            float4 a = ((const float4*)in2)[i * 2], b = ((const float4*)in2)[i * 2 + 1];
            union { uint4 u; bf16 h[8]; } r;
            r.h[0] = __float2bfloat16(a.x); r.h[1] = __float2bfloat16(a.y);
            r.h[2] = __float2bfloat16(a.z); r.h[3] = __float2bfloat16(a.w);
            r.h[4] = __float2bfloat16(b.x); r.h[5] = __float2bfloat16(b.y);
            r.h[6] = __float2bfloat16(b.z); r.h[7] = __float2bfloat16(b.w);
            ((uint4*)out2)[i] = r.u;
        }
    }
}

// vw_l [h][e][d] f32 -> wzv[h][512+e][d] bf16 (V half of per-head [H;Wv])
__global__ void k_prep_wv(const float* __restrict__ vw, bf16* __restrict__ wzv) {
    int idx = blockIdx.x * blockDim.x + threadIdx.x;   // [h][e][d8]
    if (idx >= NH_ * D_ * (D_ / 8)) return;
    int d8 = idx & 63;
    int e  = (idx >> 6) & 511;
    int h  = idx >> 15;
    long so = ((long)(h * D_ + e)) * D_ + d8 * 8;
    float4 a = *(const float4*)(vw + so), b = *(const float4*)(vw + so + 4);
    union { uint4 u; bf16 hh[8]; } rr;
    rr.hh[0] = __float2bfloat16(a.x); rr.hh[1] = __float2bfloat16(a.y);
    rr.hh[2] = __float2bfloat16(a.z); rr.hh[3] = __float2bfloat16(a.w);
    rr.hh[4] = __float2bfloat16(b.x); rr.hh[5] = __float2bfloat16(b.y);
    rr.hh[6] = __float2bfloat16(b.z); rr.hh[7] = __float2bfloat16(b.w);
    ((uint4*)wzv)[((long)(h * 1024 + 512 + e)) * 64 + d8] = rr.u;
}

// bias vector, wave-parallel: wave per (h,j<512) computes u[j]=sum_e kw[h][e][j]*qb[h][e];
// tail waves copy vb into the upper half.
__global__ __launch_bounds__(256) void k_prep_ub(const float* __restrict__ kw,
        const float* __restrict__ qb, const float* __restrict__ vb, float* __restrict__ out) {
    int gw = blockIdx.x * 4 + (threadIdx.x >> 6);
    int lane = threadIdx.x & 63;
    if (gw < NH_ * 512) {
        int h = gw >> 9, j = gw & 511;
        const float* kwh = kw + (long)h * D_ * D_ + j;
        const float* qbh = qb + h * D_;
        float s = 0.f;
#pragma unroll
        for (int i = 0; i < 8; i++) {
            int e = i * 64 + lane;
            s += kwh[(long)e * D_] * qbh[e];
        }
#pragma unroll
        for (int off = 32; off; off >>= 1) s += __shfl_xor(s, off, 64);
        if (lane == 0) out[h * 1024 + j] = s;
    } else {
        int t = (gw - NH_ * 512) * 64 + lane;
        if (t < NH_ * 512) {
            int h = t >> 9, j = t & 511;
            out[h * 1024 + 512 + j] = vb[h * D_ + j];
        }
    }
}

__global__ void k_patchify(const float* __restrict__ img, bf16* __restrict__ patches) {
    long idx = (long)blockIdx.x * blockDim.x + threadIdx.x;
    long total = (long)B_ * 196 * 256;
    if (idx >= total) return;
    int q = (int)(idx & 255);
    int p = (int)((idx >> 8) % 196);
    int b = (int)(idx / (196 * 256));
    int gy = p / GP_, gx = p % GP_;
    int py = q >> 4,  px = q & 15;
    patches[idx] = __float2bfloat16(img[((long)b * HW_ + gy * P_ + py) * HW_ + gx * P_ + px]);
}

__global__ void k_cls_token(const float* __restrict__ tok, float* __restrict__ x) {
    int i = blockIdx.x * blockDim.x + threadIdx.x;
    if (i < B_ * D_) {
        int b = i >> 9, d = i & 511;
        x[(long)b * T_ * D_ + d] = tok[d];
    }
}

// map_w[l] is [T][T*NH]; per-head zero-K-padded A: out[h][t][s] (lda=TP_)
__global__ void k_prep_map(const float* __restrict__ in, bf16* __restrict__ out) {
    int idx = blockIdx.x * blockDim.x + threadIdx.x;
    int total = NH_ * T_ * TP_;
    if (idx >= total) return;
    int s = idx % TP_;
    int t = (idx / TP_) % T_;
    int h = idx / (TP_ * T_);
    float v = (s < T_) ? in[t * (T_ * NH_) + h * T_ + s] : 0.f;
    out[idx] = __float2bfloat16(v);
}

// ---------------- LayerNorm (one wave per row of 512) ----------------

template<int WRITE_Y>
__global__ __launch_bounds__(256) void k_ln(const float* x,
        const float* __restrict__ g, const float* __restrict__ bb,
        bf16* __restrict__ obf, float* of, int rows) {
    int wid = blockIdx.x * 4 + (threadIdx.x >> 6);
    if (wid >= rows) return;
    int lane = threadIdx.x & 63;
    const float* xr = x + (long)wid * D_;
    float v[8];
    float s = 0.f;
#pragma unroll
    for (int i = 0; i < 8; i++) { v[i] = xr[i * 64 + lane]; s += v[i]; }
#pragma unroll
    for (int off = 32; off; off >>= 1) s += __shfl_xor(s, off, 64);
    float mean = s * (1.f / D_);
    float sq = 0.f;
#pragma unroll
    for (int i = 0; i < 8; i++) { float d = v[i] - mean; sq += d * d; }
#pragma unroll
    for (int off = 32; off; off >>= 1) sq += __shfl_xor(sq, off, 64);
    float inv = rsqrtf(sq * (1.f / D_) + EPS_);
#pragma unroll
    for (int i = 0; i < 8; i++) {
        int d = i * 64 + lane;
        float val = (v[i] - mean) * inv * g[d] + bb[d];
        obf[(long)wid * D_ + d] = __float2bfloat16(val);
        if (WRITE_Y) of[(long)wid * D_ + d] = val;
    }
}

// ---- fused 2-head S = Z K^T (scaled) + row-softmax -> P (bf16, zero-padded) ----
// LDS col-group swizzle g^((row>>1)&3): linear dest + pre-swizzled source + swizzled read.

__global__ __launch_bounds__(256) void k_attn_ssm2(
        const bf16* __restrict__ Qbase, long ldq, long qImg, long qHead,
        const bf16* __restrict__ Kbase, long ldk, long kImg,
        bf16* __restrict__ Pm, float scale) {
    __shared__ __align__(16) bf16 Qs[128][32];
    __shared__ __align__(16) bf16 Ks[256][32];
    int z = blockIdx.z;
    int img = z & 127, h2 = z >> 7;
    int q0 = blockIdx.y * 128;
    int tid = threadIdx.x;
    int wv = tid >> 6, lane = tid & 63;

    const bf16* Qp = Qbase + (long)img * qImg + (long)h2 * qHead;
    const bf16* Kp = Kbase + (long)img * kImg;

    int sRow = 16 * wv + (lane >> 2);
    int sCol = ((lane & 3) ^ ((lane >> 3) & 3)) * 8;   // inverse-swizzled source col
    const bf16* gQ = Qp + (long)(q0 + sRow) * ldq + sCol;
    const bf16* gK = Kp + (long)sRow * ldk + sCol;
    char* lQ = (char*)Qs + (16 * wv) * 64;
    char* lK = (char*)Ks + (16 * wv) * 64;

    f32x4 acc[2][13];
#pragma unroll
    for (int j = 0; j < 2; j++)
#pragma unroll
        for (int f = 0; f < 13; f++) acc[j][f] = (f32x4){0.f, 0.f, 0.f, 0.f};

    int kgrp = lane >> 4;
#pragma unroll
    for (int kt = 0; kt < 16; kt++) {
        long k0 = (long)kt * 32;
        gload16(gQ + k0, lQ);
        gload16(gQ + 64 * ldq + k0, lQ + 4096);
#pragma unroll
        for (int p = 0; p < 4; p++)
            gload16(gK + (long)(p * 64) * ldk + k0, lK + p * 4096);
        __syncthreads();
        bf16x8 af[2];
#pragma unroll
        for (int j = 0; j < 2; j++) {
            int R = wv * 32 + j * 16 + (lane & 15);
            af[j] = *(const bf16x8*)&Qs[R][(kgrp ^ ((R >> 1) & 3)) * 8];
        }
#pragma unroll
        for (int f = 0; f < 13; f++) {
            int R = f * 16 + (lane & 15);
            bf16x8 bfr = *(const bf16x8*)&Ks[R][(kgrp ^ ((R >> 1) & 3)) * 8];
            acc[0][f] = __builtin_amdgcn_mfma_f32_16x16x32_bf16(af[0], bfr, acc[0][f], 0, 0, 0);
            acc[1][f] = __builtin_amdgcn_mfma_f32_16x16x32_bf16(af[1], bfr, acc[1][f], 0, 0, 0);
        }
        __syncthreads();
    }

    int c1 = lane & 15, grp = lane >> 4;
    const bf16 z0 = __float2bfloat16(0.f);
#pragma unroll
    for (int j = 0; j < 2; j++) {
        float mx[4] = {-1e30f, -1e30f, -1e30f, -1e30f};
        float sm[4] = {0.f, 0.f, 0.f, 0.f};
#pragma unroll
        for (int f = 0; f < 13; f++) {
            bool val = (f * 16 + c1 < T_);
#pragma unroll
            for (int r = 0; r < 4; r++) {
                float v = val ? acc[j][f][r] * scale : -1e30f;
                acc[j][f][r] = v;
                mx[r] = fmaxf(mx[r], v);
            }
        }
#pragma unroll
        for (int r = 0; r < 4; r++)
#pragma unroll
            for (int off = 1; off < 16; off <<= 1) mx[r] = fmaxf(mx[r], __shfl_xor(mx[r], off, 64));
#pragma unroll
        for (int f = 0; f < 13; f++) {
            bool val = (f * 16 + c1 < T_);
#pragma unroll
            for (int r = 0; r < 4; r++) {
                float e = val ? expf(acc[j][f][r] - mx[r]) : 0.f;
                acc[j][f][r] = e;
                sm[r] += e;
            }
        }
#pragma unroll
        for (int r = 0; r < 4; r++) {
#pragma unroll
            for (int off = 1; off < 16; off <<= 1) sm[r] += __shfl_xor(sm[r], off, 64);
            sm[r] = 1.f / sm[r];
        }
#pragma unroll
        for (int r = 0; r < 4; r++) {
            int qi = q0 + wv * 32 + j * 16 + grp * 4 + r;
            if (qi >= T_) continue;
            bf16* prow = Pm + ((long)z * T_ + qi) * TP_;
#pragma unroll
            for (int f = 0; f < 13; f++)
                prow[f * 16 + c1] = __float2bfloat16(acc[j][f][r] * sm[r]);
            prow[208 + c1] = z0;
        }
    }
}

// ---------------- GEMM kernels ----------------

__device__ __forceinline__ float geluf(float v) {
    return 0.5f * v * (1.f + erff(v * 0.70710678118654752f));
}

// ===== 128x256-tile variant: 4 waves, wave = 64x128, acc 4x8, 24 KB LDS =====
// 32 MFMA per wave per K-step (2x the 128^2 core) at unchanged occupancy.
// Guard-free (exact shapes only). KT compile-time, fully unrolled.
// Swizzles identical to the verified 128^2 core. XCD swizzle always on.
// MODE 1: bf16 (v+bias)  2: bf16 gelu(v+bias)
template<int MODE, int KT>
__global__ __launch_bounds__(256) void k_gemm_bt2(
        const bf16* __restrict__ A, long lda,
        const bf16* __restrict__ Bw, long ldb,
        void* __restrict__ Cp, long ldc,
        const float* __restrict__ bias) {
    __shared__ __align__(16) bf16 As[128][32];   // 8 KB
    __shared__ __align__(16) bf16 Bs[256][32];   // 16 KB
    unsigned bx = blockIdx.x, by = blockIdx.y;
    {
        unsigned nx = gridDim.x;
        unsigned nwg = nx * gridDim.y;
        unsigned f = by * nx + bx;
        unsigned q = nwg >> 3, r = nwg & 7;
        unsigned xcd = f & 7, idx = f >> 3;
        unsigned base = (xcd < r) ? xcd * (q + 1) : r * (q + 1) + (xcd - r) * q;
        unsigned nf = base + idx;
        bx = nf % nx;
        by = nf / nx;
    }
    int m0 = by * 128, n0 = bx * 256;

    int tid = threadIdx.x;
    int wv = tid >> 6, lane = tid & 63;
    int wm = (wv >> 1) * 64, wn = (wv & 1) * 128;
    int lrow = lane & 15, kgrp = lane >> 4;

    int rA = tid >> 2;
    int pA = (((tid & 3) ^ ((tid >> 3) & 3))) * 8;     // inverse-swizzled source col
    const bf16* gA0 = A  + (long)(m0 + rA) * lda + pA;
    const bf16* gB0 = Bw + (long)(n0 + rA) * ldb + pA;
    char* lA = (char*)As + (wv * 64) * 16;
    char* lB = (char*)Bs + (wv * 64) * 16;

    f32x4 acc[4][8];
#pragma unroll
    for (int i = 0; i < 4; i++)
#pragma unroll
        for (int j = 0; j < 8; j++) acc[i][j] = (f32x4){0.f, 0.f, 0.f, 0.f};

#pragma unroll
    for (int kt = 0; kt < (KT >> 5); kt++) {
        const long k0 = (long)kt << 5;
        gload16(gA0 + k0, lA);
        gload16(gA0 + 64 * lda + k0, lA + 4096);
        gload16(gB0 + k0, lB);
        gload16(gB0 + 64 * ldb + k0, lB + 4096);
        gload16(gB0 + 128 * ldb + k0, lB + 8192);
        gload16(gB0 + 192 * ldb + k0, lB + 12288);
        __syncthreads();
        bf16x8 af[4], bfr[8];
#pragma unroll
        for (int mi = 0; mi < 4; mi++) {
            int R = wm + mi * 16 + lrow;
            af[mi] = *(const bf16x8*)&As[R][(kgrp ^ ((R >> 1) & 3)) * 8];
        }
#pragma unroll
        for (int ni = 0; ni < 8; ni++) {
            int R = wn + ni * 16 + lrow;
            bfr[ni] = *(const bf16x8*)&Bs[R][(kgrp ^ ((R >> 1) & 3)) * 8];
        }
#pragma unroll
        for (int mi = 0; mi < 4; mi++)
#pragma unroll
            for (int ni = 0; ni < 8; ni++)
                acc[mi][ni] = __builtin_amdgcn_mfma_f32_16x16x32_bf16(af[mi], bfr[ni], acc[mi][ni], 0, 0, 0);
        __syncthreads();
    }

    int r4 = (lane >> 4) * 4, c1 = lane & 15;
    float bv[8];
#pragma unroll
    for (int ni = 0; ni < 8; ni++)
        bv[ni] = bias ? bias[n0 + wn + ni * 16 + c1] : 0.f;
#pragma unroll
    for (int mi = 0; mi < 4; mi++) {
#pragma unroll
        for (int r = 0; r < 4; r++) {
            long row = m0 + wm + mi * 16 + r4 + r;
            long base = row * ldc + n0 + wn + c1;
#pragma unroll
            for (int ni = 0; ni < 8; ni++) {
                float v = acc[mi][ni][r] + bv[ni];
                long cidx = base + ni * 16;
                if (MODE == 1) ((bf16*)Cp)[cidx] = __float2bfloat16(v);
                else           ((bf16*)Cp)[cidx] = __float2bfloat16(geluf(v));
            }
        }
    }
}

// C[M,N] = A[M,K] @ B[N,K]^T.  128^2 core (R16-proven): depth-3 rotating buffers +
// counted vmcnt(4) + single raw barrier per iter. KT fully unrolled.
// MODE 0: f32 (v+bias?)  1: bf16 (v+bias)  2: bf16 gelu(v+bias)  3: f32 (v+bias+res)
template<int MODE, bool GUARD, bool SWZ, int KT>
__global__ __launch_bounds__(256) void k_gemm_bt(
        const bf16* __restrict__ A, long lda, long bsA,
        const bf16* __restrict__ Bw, long ldb, long bsB,
        void* __restrict__ Cp, long ldc, long bsC,
        const float* __restrict__ bias,
        const float* res, long ldres,
        int Mt, int Nt) {
    __shared__ __align__(16) bf16 As[3][128][32];   // 3 x 8 KB
    __shared__ __align__(16) bf16 Bs[3][128][32];   // 3 x 8 KB  (48 KB total)
    int bz = blockIdx.z;
    A  += (long)bz * bsA;
    Bw += (long)bz * bsB;

    unsigned bx = blockIdx.x, by = blockIdx.y;
    if (SWZ) {
        unsigned nx = gridDim.x;
        unsigned nwg = nx * gridDim.y;
        unsigned f = by * nx + bx;
        unsigned q = nwg >> 3, r = nwg & 7;
        unsigned xcd = f & 7, idx = f >> 3;
        unsigned base = (xcd < r) ? xcd * (q + 1) : r * (q + 1) + (xcd - r) * q;
        unsigned nf = base + idx;
        bx = nf % nx;
        by = nf / nx;
    }
    int m0 = by * 128, n0 = bx * 128;

    int tid = threadIdx.x;
    int wv = tid >> 6, lane = tid & 63;
    int wm = (wv >> 1) * 64, wn = (wv & 1) * 64;
    int lrow = lane & 15, kgrp = lane >> 4;

    int rA = tid >> 2;
    int pA = (((tid & 3) ^ ((tid >> 3) & 3))) * 8;     // inverse-swizzled source col
    const bf16* gA0 = A  + (long)(m0 + rA) * lda + pA;
    const bf16* gA1 = A  + (long)(m0 + 64 + rA) * lda + pA;
    const bf16* gB0 = Bw + (long)(n0 + rA) * ldb + pA;
    const bf16* gB1 = Bw + (long)(n0 + 64 + rA) * ldb + pA;
    char* lA0 = (char*)As + (wv * 64) * 16;
    char* lA1 = (char*)As + (256 + wv * 64) * 16;
    char* lB0 = (char*)Bs + (wv * 64) * 16;
    char* lB1 = (char*)Bs + (256 + wv * 64) * 16;

    auto stage = [&](int buf, int kt) {    // 4 gload16 per thread (phantom past K ok)
        const long k0 = (long)kt << 5;
        const int bo = buf * 8192;
        gload16(gA0 + k0, lA0 + bo);
        gload16(gA1 + k0, lA1 + bo);
        gload16(gB0 + k0, lB0 + bo);
        gload16(gB1 + k0, lB1 + bo);
    };

    f32x4 acc[4][4];
#pragma unroll
    for (int i = 0; i < 4; i++)
#pragma unroll
        for (int j = 0; j < 4; j++) acc[i][j] = (f32x4){0.f, 0.f, 0.f, 0.f};

    stage(0, 0);
    stage(1, 1);
    asm volatile("s_waitcnt vmcnt(4)" ::: "memory");   // tile 0 landed (own)
    SCHED0_; __builtin_amdgcn_s_barrier(); SCHED0_;

#pragma unroll
    for (int kt = 0; kt < (KT >> 5); kt++) {
        stage((kt + 2) % 3, kt + 2);       // buffer freed by barrier at end of kt-1
        const int c = kt % 3;
        bf16x8 af[4], bfr[4];
#pragma unroll
        for (int mi = 0; mi < 4; mi++) {
            int R = wm + mi * 16 + lrow;
            af[mi] = *(const bf16x8*)&As[c][R][(kgrp ^ ((R >> 1) & 3)) * 8];
        }
#pragma unroll
        for (int ni = 0; ni < 4; ni++) {
            int R = wn + ni * 16 + lrow;
            bfr[ni] = *(const bf16x8*)&Bs[c][R][(kgrp ^ ((R >> 1) & 3)) * 8];
        }
#pragma unroll
        for (int mi = 0; mi < 4; mi++)
#pragma unroll
            for (int ni = 0; ni < 4; ni++)
                acc[mi][ni] = __builtin_amdgcn_mfma_f32_16x16x32_bf16(af[mi], bfr[ni], acc[mi][ni], 0, 0, 0);
        SCHED0_;
        asm volatile("s_waitcnt vmcnt(4)" ::: "memory");   // tile kt+1 landed (own)
        SCHED0_; __builtin_amdgcn_s_barrier(); SCHED0_;    // block-wide: kt+1 ready
    }
    asm volatile("s_waitcnt vmcnt(0)" ::: "memory");       // drain phantoms before exit

    int r4 = (lane >> 4) * 4, c1 = lane & 15;
    float bv[4];
#pragma unroll
    for (int ni = 0; ni < 4; ni++) {
        int col = n0 + wn + ni * 16 + c1;
        bv[ni] = (bias && (!GUARD || col < Nt)) ? bias[col] : 0.f;
    }
#pragma unroll
    for (int mi = 0; mi < 4; mi++) {
#pragma unroll
        for (int r = 0; r < 4; r++) {
            int row = m0 + wm + mi * 16 + r4 + r;
            if (GUARD && row >= Mt) continue;
            long base = (long)bz * bsC + (long)row * ldc + n0 + wn + c1;
#pragma unroll
            for (int ni = 0; ni < 4; ni++) {
                if (GUARD && (n0 + wn + ni * 16 + c1) >= Nt) continue;
                float v = acc[mi][ni][r] + bv[ni];
                long cidx = base + ni * 16;
                if (MODE == 0)      ((float*)Cp)[cidx] = v;
                else if (MODE == 1) ((bf16*)Cp)[cidx]  = __float2bfloat16(v);
                else if (MODE == 2) ((bf16*)Cp)[cidx]  = __float2bfloat16(geluf(v));
                else                ((float*)Cp)[cidx] = v + res[(long)row * ldres + n0 + wn + c1 + ni * 16];
            }
        }
    }
}

// R = map_pair @ P (both heads, one launch). z: img=z&127, h2=z>>7.
__global__ __launch_bounds__(256) void k_gemm_r(
        const bf16* __restrict__ mapPair,      // [2][T][TP_]
        const bf16* __restrict__ Pb,           // [256][T][TP_]
        bf16* __restrict__ Rcat) {             // [128][224][448]
    __shared__ __align__(16) bf16 As[128][32];
    __shared__ __align__(16) bf16 Bs[128][32];
    int z = blockIdx.z;
    int img = z & 127, h2 = z >> 7;
    const bf16* A  = mapPair + (long)h2 * T_ * TP_;
    const bf16* Bw = Pb + ((long)(h2 * 128 + img)) * (long)T_ * TP_;
    bf16* Cp = Rcat + (long)img * 224 * RCW_ + h2 * 224;
    int m0 = blockIdx.y * 128, n0 = blockIdx.x * 128;
    int tid = threadIdx.x;
    int wv = tid >> 6, lane = tid & 63;
    int wm = (wv >> 1) * 64, wn = (wv & 1) * 64;
    int lrow = lane & 15, koff = (lane >> 4) * 8;

    int rA = tid >> 2, pA = (tid & 3) * 8;
    const bf16* gA0 = A + (long)(m0 + rA) * TP_ + pA;
    const bf16* gA1 = A + (long)(m0 + 64 + rA) * TP_ + pA;
    char* lA0 = (char*)As + (wv * 64) * 16;
    char* lA1 = (char*)As + (256 + wv * 64) * 16;
    int bk = tid & 31, bg = tid >> 5;

    f32x4 acc[4][4];
#pragma unroll
    for (int i = 0; i < 4; i++)
#pragma unroll
        for (int j = 0; j < 4; j++) acc[i][j] = (f32x4){0.f, 0.f, 0.f, 0.f};

#pragma unroll
    for (int kt = 0; kt < 7; kt++) {
        long k0 = (long)kt << 5;
        gload16(gA0 + k0, lA0);
        gload16(gA1 + k0, lA1);
#pragma unroll
        for (int i = 0; i < 2; i++) {
            int g = bg + 8 * i;
            uint4 v = *(const uint4*)(Bw + (k0 + bk) * TP_ + n0 + g * 8);
            const bf16* pv = (const bf16*)&v;
#pragma unroll
            for (int j = 0; j < 8; j++) Bs[g * 8 + j][bk] = pv[j];
        }
        __syncthreads();
        bf16x8 af[4], bfr[4];
#pragma unroll
        for (int mi = 0; mi < 4; mi++) af[mi]  = *(const bf16x8*)&As[wm + mi * 16 + lrow][koff];
#pragma unroll
        for (int ni = 0; ni < 4; ni++) bfr[ni] = *(const bf16x8*)&Bs[wn + ni * 16 + lrow][koff];
#pragma unroll
        for (int mi = 0; mi < 4; mi++)
#pragma unroll
            for (int ni = 0; ni < 4; ni++)
                acc[mi][ni] = __builtin_amdgcn_mfma_f32_16x16x32_bf16(af[mi], bfr[ni], acc[mi][ni], 0, 0, 0);
        __syncthreads();
    }

    int r4 = (lane >> 4) * 4, c1 = lane & 15;
#pragma unroll
    for (int mi = 0; mi < 4; mi++) {
#pragma unroll
        for (int r = 0; r < 4; r++) {
            int row = m0 + wm + mi * 16 + r4 + r;
            if (row >= T_) continue;
#pragma unroll
            for (int ni = 0; ni < 4; ni++) {
                int col = n0 + wn + ni * 16 + c1;
                if (col >= 224) continue;
                Cp[(long)row * RCW_ + col] = __float2bfloat16(acc[mi][ni][r]);
            }
        }
    }
}

// x += Rcat @ [V0;V1] (K=448 concat) + optional rowbias. z = img.
__global__ __launch_bounds__(256) void k_gemm_rv(
        const bf16* __restrict__ Rcat,         // [128][224][448]
        const bf16* __restrict__ ZV,           // [BT][2048]; V0 at +512, V1 at +1536
        float* __restrict__ xf,
        const float* __restrict__ rowbias) {
    __shared__ __align__(16) bf16 As[128][32];
    __shared__ __align__(16) bf16 Bs[128][32];
    int img = blockIdx.z;
    const bf16* A = Rcat + (long)img * 224 * RCW_;
    const bf16* Vimg = ZV + (long)img * T_ * ZVW2_;
    float* Cp = xf + (long)img * T_ * D_;
    int m0 = blockIdx.y * 128, n0 = blockIdx.x * 128;
    int tid = threadIdx.x;
    int wv = tid >> 6, lane = tid & 63;
    int wm = (wv >> 1) * 64, wn = (wv & 1) * 64;
    int lrow = lane & 15, koff = (lane >> 4) * 8;

    int rA = tid >> 2, pA = (tid & 3) * 8;
    const bf16* gA0 = A + (long)(m0 + rA) * RCW_ + pA;
    const bf16* gA1 = A + (long)(m0 + 64 + rA) * RCW_ + pA;
    char* lA0 = (char*)As + (wv * 64) * 16;
    char* lA1 = (char*)As + (256 + wv * 64) * 16;
    int bk = tid & 31, bg = tid >> 5;

    f32x4 acc[4][4];
#pragma unroll
    for (int i = 0; i < 4; i++)
#pragma unroll
        for (int j = 0; j < 4; j++) acc[i][j] = (f32x4){0.f, 0.f, 0.f, 0.f};

#pragma unroll
    for (int kt = 0; kt < 14; kt++) {
        long k0 = (long)kt << 5;
        gload16(gA0 + k0, lA0);
        gload16(gA1 + k0, lA1);
        const bf16* Vb = (kt < 7) ? (Vimg + 512 + k0 * ZVW2_)
                                  : (Vimg + 1536 + (k0 - 224) * ZVW2_);
#pragma unroll
        for (int i = 0; i < 2; i++) {
            int g = bg + 8 * i;
            uint4 v = *(const uint4*)(Vb + (long)bk * ZVW2_ + n0 + g * 8);
            const bf16* pv = (const bf16*)&v;
#pragma unroll
            for (int j = 0; j < 8; j++) Bs[g * 8 + j][bk] = pv[j];
        }
        __syncthreads();
        bf16x8 af[4], bfr[4];
#pragma unroll
        for (int mi = 0; mi < 4; mi++) af[mi]  = *(const bf16x8*)&As[wm + mi * 16 + lrow][koff];
#pragma unroll
        for (int ni = 0; ni < 4; ni++) bfr[ni] = *(const bf16x8*)&Bs[wn + ni * 16 + lrow][koff];
#pragma unroll
        for (int mi = 0; mi < 4; mi++)
#pragma unroll
            for (int ni = 0; ni < 4; ni++)
                acc[mi][ni] = __builtin_amdgcn_mfma_f32_16x16x32_bf16(af[mi], bfr[ni], acc[mi][ni], 0, 0, 0);
        __syncthreads();
    }

    int r4 = (lane >> 4) * 4, c1 = lane & 15;
#pragma unroll
    for (int mi = 0; mi < 4; mi++) {
#pragma unroll
        for (int r = 0; r < 4; r++) {
            int row = m0 + wm + mi * 16 + r4 + r;
            if (row >= T_) continue;
            float rb = rowbias ? rowbias[row] : 0.f;
#pragma unroll
            for (int ni = 0; ni < 4; ni++) {
                int col = n0 + wn + ni * 16 + c1;
                Cp[(long)row * D_ + col] += acc[mi][ni][r] + rb * 0.25f;
            }
        }
    }
}

// C[M,N] = A^T @ B. A [K][M], B [K][N] row-major, bf16 store. K%32==0.
__global__ __launch_bounds__(256) void k_gemm_tn(
        const bf16* __restrict__ A, long lda, long bsA,
        const bf16* __restrict__ Bw, long ldb, long bsB,
        bf16* __restrict__ Cp, long ldc, long bsC,
        int Mt, int Nt, int Kt) {
    __shared__ __align__(16) bf16 As[128][32];
    __shared__ __align__(16) bf16 Bs[128][32];
    int bz = blockIdx.z;
    A  += (long)bz * bsA;
    Bw += (long)bz * bsB;
    int m0 = blockIdx.y * 128, n0 = blockIdx.x * 128;
    int tid = threadIdx.x;
    int wv = tid >> 6, lane = tid & 63;
    int wm = (wv >> 1) * 64, wn = (wv & 1) * 64;
    int lrow = lane & 15, koff = (lane >> 4) * 8;
    int bk = tid & 31, bg = tid >> 5;

    f32x4 acc[4][4];
#pragma unroll
    for (int i = 0; i < 4; i++)
#pragma unroll
        for (int j = 0; j < 4; j++) acc[i][j] = (f32x4){0.f, 0.f, 0.f, 0.f};

    int kTiles = Kt >> 5;
    for (int kt = 0; kt < kTiles; kt++) {
        long k0 = (long)kt << 5;
#pragma unroll
        for (int i = 0; i < 2; i++) {
            int g = bg + 8 * i;
            uint4 va = *(const uint4*)(A + (k0 + bk) * lda + m0 + g * 8);
            const bf16* pa = (const bf16*)&va;
#pragma unroll
            for (int j = 0; j < 8; j++) As[g * 8 + j][bk] = pa[j];
            uint4 vb = *(const uint4*)(Bw + (k0 + bk) * ldb + n0 + g * 8);
            const bf16* pb = (const bf16*)&vb;
#pragma unroll
            for (int j = 0; j < 8; j++) Bs[g * 8 + j][bk] = pb[j];
        }
        __syncthreads();
        bf16x8 af[4], bfr[4];
#pragma unroll
        for (int mi = 0; mi < 4; mi++) af[mi]  = *(const bf16x8*)&As[wm + mi * 16 + lrow][koff];
#pragma unroll
        for (int ni = 0; ni < 4; ni++) bfr[ni] = *(const bf16x8*)&Bs[wn + ni * 16 + lrow][koff];
#pragma unroll
        for (int mi = 0; mi < 4; mi++)
#pragma unroll
            for (int ni = 0; ni < 4; ni++)
                acc[mi][ni] = __builtin_amdgcn_mfma_f32_16x16x32_bf16(af[mi], bfr[ni], acc[mi][ni], 0, 0, 0);
        __syncthreads();
    }

    int r4 = (lane >> 4) * 4, c1 = lane & 15;
#pragma unroll
    for (int mi = 0; mi < 4; mi++) {
#pragma unroll
        for (int r = 0; r < 4; r++) {
            int row = m0 + wm + mi * 16 + r4 + r;
            if (row >= Mt) continue;
#pragma unroll
            for (int ni = 0; ni < 4; ni++) {
                int col = n0 + wn + ni * 16 + c1;
                if (col >= Nt) continue;
                Cp[(long)bz * bsC + (long)row * ldc + col] = __float2bfloat16(acc[mi][ni][r]);
            }
        }
    }
}

// ---------------- classifier + softmax ----------------

__global__ __launch_bounds__(64) void k_classifier(const float* __restrict__ x,
        const float* __restrict__ w, const float* __restrict__ bias, float* __restrict__ out) {
    int b = blockIdx.x, lane = threadIdx.x;
    const float* xr = x + (long)b * T_ * D_;
    float logits[NC_];
#pragma unroll
    for (int c = 0; c < NC_; c++) {
        float s = 0.f;
        for (int d = lane; d < D_; d += 64) s += xr[d] * w[c * D_ + d];
#pragma unroll
        for (int off = 32; off; off >>= 1) s += __shfl_xor(s, off, 64);
        logits[c] = s + bias[c];
    }
    float mx = -1e30f;
#pragma unroll
    for (int c = 0; c < NC_; c++) mx = fmaxf(mx, logits[c]);
    float sum = 0.f;
#pragma unroll
    for (int c = 0; c < NC_; c++) { float e = expf(logits[c] - mx); logits[c] = e; sum += e; }
    if (lane == 0) {
        float inv = 1.f / sum;
#pragma unroll
        for (int c = 0; c < NC_; c++) out[(long)b * NC_ + c] = logits[c] * inv;
    }
}

// ---------------- host ----------------

extern "C" void kernel_launch(void* const* d_in, const int* in_sizes, int n_in,
                              void* d_out, int out_size, void* d_ws, size_t ws_size,
                              hipStream_t stream) {
    const float* images  = (const float*)d_in[0];
    const float* lin_w   = (const float*)d_in[1];
    const float* lin_b   = (const float*)d_in[2];
    const float* cls_tok = (const float*)d_in[3];
    const float* ln1_g   = (const float*)d_in[4];
    const float* ln1_b   = (const float*)d_in[5];
    const float* ln2_g   = (const float*)d_in[6];
    const float* ln2_b   = (const float*)d_in[7];
    const float* qw      = (const float*)d_in[8];
    const float* qb      = (const float*)d_in[9];
    const float* kw      = (const float*)d_in[10];
    const float* kb      = (const float*)d_in[11];
    const float* vw      = (const float*)d_in[12];
    const float* vb      = (const float*)d_in[13];
    const float* map_w   = (const float*)d_in[14];
    const float* map_b   = (const float*)d_in[15];
    const float* w1      = (const float*)d_in[16];
    const float* b1      = (const float*)d_in[17];
    const float* w2      = (const float*)d_in[18];
    const float* b2      = (const float*)d_in[19];
    const float* cls_w   = (const float*)d_in[20];
    const float* cls_b   = (const float*)d_in[21];

    char* wp = (char*)d_ws;
    auto alloc = [&](size_t bytes) { char* p = wp; wp += (bytes + 255) & ~(size_t)255; return p; };
    const long BT = (long)B_ * T_;                       // 25216 = 197*128 exactly

    // ~244 MB total. Pads absorb guard-free tile overreads + phantom K-prefetch.
    float* xf   = (float*)alloc(BT * D_ * 4);
    bf16*  hb   = (bf16*) alloc((BT + 192) * D_ * 2);
    bf16*  ZVh2 = (bf16*) alloc((size_t)(BT + 160) * ZVW2_ * 2);    // 2-head Z|V ∪ m1 (MLP)
    bf16*  m1c  = ZVh2;
    bf16*  Pb2  = (bf16*) alloc(((size_t)256 * T_ + 64) * TP_ * 2); // both heads' P
    char*  rcReg= alloc(((size_t)128 * 224 + 64) * RCW_ * 2);       // Rcat ∪ patches ∪ wqb/wkb
    bf16*  Rcat = (bf16*)rcReg;
    bf16*  patches = (bf16*)rcReg;
    bf16*  wqb  = (bf16*)rcReg;
    bf16*  wkb  = (bf16*)(rcReg + (long)NH_ * D_ * D_ * 2);
    bf16*  wzv  = (bf16*) alloc(((long)NH_ * 1024 + 64) * D_ * 2);
    float* zvb  = (float*)alloc((long)NH_ * 1024 * 4);
    bf16*  wmapP= (bf16*) alloc(((long)NH_ * T_ + 64) * TP_ * 2);
    bf16*  w1l  = (bf16*) alloc((long)(M_ + 64) * D_ * 2);
    bf16*  w2l  = (bf16*) alloc((long)(D_ + 64) * M_ * 2);
    bf16*  wlin = (bf16*) alloc((long)(D_ + 64) * 256 * 2);

    k_f32_to_bf16v<<<1024, 256, 0, stream>>>(lin_w, wlin, (long)D_ * 256 / 8);
    {
        long tot = (long)B_ * 196 * 256;
        k_patchify<<<(int)((tot + 255) / 256), 256, 0, stream>>>(images, patches);
        k_cls_token<<<(B_ * D_ + 255) / 256, 256, 0, stream>>>(cls_tok, xf);
        k_gemm_bt<0, true, false, 256><<<dim3(4, 2, B_), 256, 0, stream>>>(
            patches, 256, (long)196 * 256,
            wlin, 256, 0,
            xf + D_, D_, (long)T_ * D_,
            lin_b, nullptr, 0,
            196, D_);
    }

    const float scale = 1.0f / 14.0f;
    const int lnGrid = (int)((BT + 3) / 4);

    for (int l = 0; l < L_; l++) {
        // ---- per-layer weight prep ----
        k_f32_to_bf16v2<<<1024, 256, 0, stream>>>(
            qw + (long)l * NH_ * D_ * D_, wqb,
            kw + (long)l * NH_ * D_ * D_, wkb, (long)NH_ * D_ * D_ / 8);
        k_gemm_tn<<<dim3(4, 4, NH_), 256, 0, stream>>>(
            wkb, D_, (long)D_ * D_,
            wqb, D_, (long)D_ * D_,
            wzv, D_, (long)1024 * D_,
            D_, D_, D_);
        k_prep_wv<<<(NH_ * D_ * (D_ / 8) + 255) / 256, 256, 0, stream>>>(
            vw + (long)l * NH_ * D_ * D_, wzv);
        k_prep_ub<<<(NH_ * 512 + NH_ * 8 + 3) / 4, 256, 0, stream>>>(
            kw + (long)l * NH_ * D_ * D_, qb + (long)l * NH_ * D_,
            vb + (long)l * NH_ * D_, zvb);
        k_f32_to_bf16v2<<<1024, 256, 0, stream>>>(
            w1 + (long)l * M_ * D_, w1l,
            w2 + (long)l * D_ * M_, w2l, (long)M_ * D_ / 8);
        k_prep_map<<<(NH_ * T_ * TP_ + 255) / 256, 256, 0, stream>>>(
            map_w + (long)l * T_ * T_ * NH_, wmapP);

        k_ln<0><<<lnGrid, 256, 0, stream>>>(xf, ln1_g + l * D_, ln1_b + l * D_, hb, nullptr, (int)BT);

        for (int hp = 0; hp < 4; hp++) {
            // fused 2-head [Z0|V0|Z1|V1] = hb @ Wpair^T + bias (128x256 tile, N=2048)
            k_gemm_bt2<1, 512><<<dim3(8, 197), 256, 0, stream>>>(
                hb, D_, wzv + (long)hp * 2048 * D_, D_,
                ZVh2, ZVW2_, zvb + (long)hp * 2048);

            // P for both heads: z = h2*128 + img
            k_attn_ssm2<<<dim3(1, 2, 256), 256, 0, stream>>>(
                ZVh2, ZVW2_, (long)T_ * ZVW2_, 1024,
                hb, D_, (long)T_ * D_,
                Pb2, scale);

            // Rcat = [map_h0 @ P_h0 | map_h1 @ P_h1]  (one launch, both heads)
            k_gemm_r<<<dim3(2, 2, 256), 256, 0, stream>>>(
                wmapP + (long)(hp * 2) * T_ * TP_, Pb2, Rcat);

            // x += Rcat @ [V0;V1]  (K=448; map_b rowbias spread over 4 pair-launches)
            k_gemm_rv<<<dim3(4, 2, B_), 256, 0, stream>>>(
                Rcat, ZVh2, xf, map_b + (long)l * T_);
        }

        // y = LN2(x): bf16 -> hb, f32 in-place over xf
        k_ln<1><<<lnGrid, 256, 0, stream>>>(xf, ln2_g + l * D_, ln2_b + l * D_, hb, xf, (int)BT);

        // MLP: FC1 on 128x256 tile; FC2 on 128^2 (N=512 needs block count)
        k_gemm_bt2<2, 512><<<dim3(8, 197), 256, 0, stream>>>(
            hb, D_, w1l, D_, m1c, M_, b1 + (long)l * M_);
        k_gemm_bt<3, false, true, 2048><<<dim3(4, 197, 1), 256, 0, stream>>>(
            m1c, M_, 0, w2l, M_, 0,
            xf, D_, 0, b2 + (long)l * D_, xf, D_, (int)BT, D_);
    }

    k_classifier<<<B_, 64, 0, stream>>>(xf, cls_w, cls_b, (float*)d_out);
}

// Round 18
// 7191.084 us; speedup vs baseline: 1.2499x; 1.2499x over previous
//
#include <hip/hip_runtime.h>
#include <hip/hip_bf16.h>
#include <math.h>

#define B_   128
#define HW_  224
#define P_   16
#define D_   512
#define NH_  8
#define L_   6
#define M_   2048
#define NC_  10
#define GP_  14
#define T_   197
#define TP_  224    // padded T (multiple of 32)
#define EPS_ 1e-5f
#define ZVW2_ 2048  // fused 2-head [Z0|V0|Z1|V1] output width
#define RCW_ 448    // Rcat width (2 heads x 224)

typedef __hip_bfloat16 bf16;
typedef __attribute__((ext_vector_type(8))) __bf16 bf16x8;
typedef __attribute__((ext_vector_type(4))) float  f32x4;

// async global->LDS, 16B per lane. LDS dest = wave-uniform base + lane*16.
__device__ __forceinline__ void gload16(const void* g, void* l) {
    __builtin_amdgcn_global_load_lds(
        (const __attribute__((address_space(1))) void*)g,
        (__attribute__((address_space(3))) void*)l, 16, 0, 0);
}

// ---------------- elementwise / prep helpers ----------------

__device__ __forceinline__ void conv8(const float* __restrict__ in, bf16* __restrict__ out, long i) {
    float4 a = ((const float4*)in)[i * 2], b = ((const float4*)in)[i * 2 + 1];
    union { uint4 u; bf16 h[8]; } r;
    r.h[0] = __float2bfloat16(a.x); r.h[1] = __float2bfloat16(a.y);
    r.h[2] = __float2bfloat16(a.z); r.h[3] = __float2bfloat16(a.w);
    r.h[4] = __float2bfloat16(b.x); r.h[5] = __float2bfloat16(b.y);
    r.h[6] = __float2bfloat16(b.z); r.h[7] = __float2bfloat16(b.w);
    ((uint4*)out)[i] = r.u;
}

__global__ void k_f32_to_bf16v(const float* __restrict__ in, bf16* __restrict__ out, long n8) {
    long stride = (long)gridDim.x * blockDim.x;
    for (long i = (long)blockIdx.x * blockDim.x + threadIdx.x; i < n8; i += stride)
        conv8(in, out, i);
}

// four conversions in one launch (qw, kw: nA x8; w1, w2: nB x8)
__global__ void k_f32_to_bf16v4(
        const float* __restrict__ i1, bf16* __restrict__ o1,
        const float* __restrict__ i2, bf16* __restrict__ o2, long nA,
        const float* __restrict__ i3, bf16* __restrict__ o3,
        const float* __restrict__ i4, bf16* __restrict__ o4, long nB) {
    long stride = (long)gridDim.x * blockDim.x;
    for (long i = (long)blockIdx.x * blockDim.x + threadIdx.x; i < nA; i += stride) {
        conv8(i1, o1, i);
        conv8(i2, o2, i);
        if (i < nB) { conv8(i3, o3, i); conv8(i4, o4, i); }
    }
}

// vw_l [h][e][d] f32 -> wzv[h][512+e][d] bf16 (V half of per-head [H;Wv])
__global__ void k_prep_wv(const float* __restrict__ vw, bf16* __restrict__ wzv) {
    int idx = blockIdx.x * blockDim.x + threadIdx.x;   // [h][e][d8]
    if (idx >= NH_ * D_ * (D_ / 8)) return;
    int d8 = idx & 63;
    int e  = (idx >> 6) & 511;
    int h  = idx >> 15;
    long so = ((long)(h * D_ + e)) * D_ + d8 * 8;
    float4 a = *(const float4*)(vw + so), b = *(const float4*)(vw + so + 4);
    union { uint4 u; bf16 hh[8]; } rr;
    rr.hh[0] = __float2bfloat16(a.x); rr.hh[1] = __float2bfloat16(a.y);
    rr.hh[2] = __float2bfloat16(a.z); rr.hh[3] = __float2bfloat16(a.w);
    rr.hh[4] = __float2bfloat16(b.x); rr.hh[5] = __float2bfloat16(b.y);
    rr.hh[6] = __float2bfloat16(b.z); rr.hh[7] = __float2bfloat16(b.w);
    ((uint4*)wzv)[((long)(h * 1024 + 512 + e)) * 64 + d8] = rr.u;
}

// bias vector, wave-parallel: wave per (h,j<512) computes u[j]=sum_e kw[h][e][j]*qb[h][e];
// tail waves copy vb into the upper half.
__global__ __launch_bounds__(256) void k_prep_ub(const float* __restrict__ kw,
        const float* __restrict__ qb, const float* __restrict__ vb, float* __restrict__ out) {
    int gw = blockIdx.x * 4 + (threadIdx.x >> 6);
    int lane = threadIdx.x & 63;
    if (gw < NH_ * 512) {
        int h = gw >> 9, j = gw & 511;
        const float* kwh = kw + (long)h * D_ * D_ + j;
        const float* qbh = qb + h * D_;
        float s = 0.f;
#pragma unroll
        for (int i = 0; i < 8; i++) {
            int e = i * 64 + lane;
            s += kwh[(long)e * D_] * qbh[e];
        }
#pragma unroll
        for (int off = 32; off; off >>= 1) s += __shfl_xor(s, off, 64);
        if (lane == 0) out[h * 1024 + j] = s;
    } else {
        int t = (gw - NH_ * 512) * 64 + lane;
        if (t < NH_ * 512) {
            int h = t >> 9, j = t & 511;
            out[h * 1024 + 512 + j] = vb[h * D_ + j];
        }
    }
}

__global__ void k_patchify(const float* __restrict__ img, bf16* __restrict__ patches) {
    long idx = (long)blockIdx.x * blockDim.x + threadIdx.x;
    long total = (long)B_ * 196 * 256;
    if (idx >= total) return;
    int q = (int)(idx & 255);
    int p = (int)((idx >> 8) % 196);
    int b = (int)(idx / (196 * 256));
    int gy = p / GP_, gx = p % GP_;
    int py = q >> 4,  px = q & 15;
    patches[idx] = __float2bfloat16(img[((long)b * HW_ + gy * P_ + py) * HW_ + gx * P_ + px]);
}

__global__ void k_cls_token(const float* __restrict__ tok, float* __restrict__ x) {
    int i = blockIdx.x * blockDim.x + threadIdx.x;
    if (i < B_ * D_) {
        int b = i >> 9, d = i & 511;
        x[(long)b * T_ * D_ + d] = tok[d];
    }
}

// map_w[l] is [T][T*NH]; per-head zero-K-padded A: out[h][t][s] (lda=TP_)
__global__ void k_prep_map(const float* __restrict__ in, bf16* __restrict__ out) {
    int idx = blockIdx.x * blockDim.x + threadIdx.x;
    int total = NH_ * T_ * TP_;
    if (idx >= total) return;
    int s = idx % TP_;
    int t = (idx / TP_) % T_;
    int h = idx / (TP_ * T_);
    float v = (s < T_) ? in[t * (T_ * NH_) + h * T_ + s] : 0.f;
    out[idx] = __float2bfloat16(v);
}

// ---------------- LayerNorm (one wave per row of 512) ----------------

template<int WRITE_Y>
__global__ __launch_bounds__(256) void k_ln(const float* x,
        const float* __restrict__ g, const float* __restrict__ bb,
        bf16* __restrict__ obf, float* of, int rows) {
    int wid = blockIdx.x * 4 + (threadIdx.x >> 6);
    if (wid >= rows) return;
    int lane = threadIdx.x & 63;
    const float* xr = x + (long)wid * D_;
    float v[8];
    float s = 0.f;
#pragma unroll
    for (int i = 0; i < 8; i++) { v[i] = xr[i * 64 + lane]; s += v[i]; }
#pragma unroll
    for (int off = 32; off; off >>= 1) s += __shfl_xor(s, off, 64);
    float mean = s * (1.f / D_);
    float sq = 0.f;
#pragma unroll
    for (int i = 0; i < 8; i++) { float d = v[i] - mean; sq += d * d; }
#pragma unroll
    for (int off = 32; off; off >>= 1) sq += __shfl_xor(sq, off, 64);
    float inv = rsqrtf(sq * (1.f / D_) + EPS_);
#pragma unroll
    for (int i = 0; i < 8; i++) {
        int d = i * 64 + lane;
        float val = (v[i] - mean) * inv * g[d] + bb[d];
        obf[(long)wid * D_ + d] = __float2bfloat16(val);
        if (WRITE_Y) of[(long)wid * D_ + d] = val;
    }
}

// ---- fused 2-head S = Z K^T (scaled) + row-softmax -> P (bf16, zero-padded) ----
// LDS col-group swizzle g^((row>>1)&3): linear dest + pre-swizzled source + swizzled read.

__global__ __launch_bounds__(256) void k_attn_ssm2(
        const bf16* __restrict__ Qbase, long ldq, long qImg, long qHead,
        const bf16* __restrict__ Kbase, long ldk, long kImg,
        bf16* __restrict__ Pm, float scale) {
    __shared__ __align__(16) bf16 Qs[128][32];
    __shared__ __align__(16) bf16 Ks[256][32];
    int z = blockIdx.z;
    int img = z & 127, h2 = z >> 7;
    int q0 = blockIdx.y * 128;
    int tid = threadIdx.x;
    int wv = tid >> 6, lane = tid & 63;

    const bf16* Qp = Qbase + (long)img * qImg + (long)h2 * qHead;
    const bf16* Kp = Kbase + (long)img * kImg;

    int sRow = 16 * wv + (lane >> 2);
    int sCol = ((lane & 3) ^ ((lane >> 3) & 3)) * 8;   // inverse-swizzled source col
    const bf16* gQ = Qp + (long)(q0 + sRow) * ldq + sCol;
    const bf16* gK = Kp + (long)sRow * ldk + sCol;
    char* lQ = (char*)Qs + (16 * wv) * 64;
    char* lK = (char*)Ks + (16 * wv) * 64;

    f32x4 acc[2][13];
#pragma unroll
    for (int j = 0; j < 2; j++)
#pragma unroll
        for (int f = 0; f < 13; f++) acc[j][f] = (f32x4){0.f, 0.f, 0.f, 0.f};

    int kgrp = lane >> 4;
#pragma unroll
    for (int kt = 0; kt < 16; kt++) {
        long k0 = (long)kt * 32;
        gload16(gQ + k0, lQ);
        gload16(gQ + 64 * ldq + k0, lQ + 4096);
#pragma unroll
        for (int p = 0; p < 4; p++)
            gload16(gK + (long)(p * 64) * ldk + k0, lK + p * 4096);
        __syncthreads();
        bf16x8 af[2];
#pragma unroll
        for (int j = 0; j < 2; j++) {
            int R = wv * 32 + j * 16 + (lane & 15);
            af[j] = *(const bf16x8*)&Qs[R][(kgrp ^ ((R >> 1) & 3)) * 8];
        }
#pragma unroll
        for (int f = 0; f < 13; f++) {
            int R = f * 16 + (lane & 15);
            bf16x8 bfr = *(const bf16x8*)&Ks[R][(kgrp ^ ((R >> 1) & 3)) * 8];
            acc[0][f] = __builtin_amdgcn_mfma_f32_16x16x32_bf16(af[0], bfr, acc[0][f], 0, 0, 0);
            acc[1][f] = __builtin_amdgcn_mfma_f32_16x16x32_bf16(af[1], bfr, acc[1][f], 0, 0, 0);
        }
        __syncthreads();
    }

    int c1 = lane & 15, grp = lane >> 4;
    const bf16 z0 = __float2bfloat16(0.f);
#pragma unroll
    for (int j = 0; j < 2; j++) {
        float mx[4] = {-1e30f, -1e30f, -1e30f, -1e30f};
        float sm[4] = {0.f, 0.f, 0.f, 0.f};
#pragma unroll
        for (int f = 0; f < 13; f++) {
            bool val = (f * 16 + c1 < T_);
#pragma unroll
            for (int r = 0; r < 4; r++) {
                float v = val ? acc[j][f][r] * scale : -1e30f;
                acc[j][f][r] = v;
                mx[r] = fmaxf(mx[r], v);
            }
        }
#pragma unroll
        for (int r = 0; r < 4; r++)
#pragma unroll
            for (int off = 1; off < 16; off <<= 1) mx[r] = fmaxf(mx[r], __shfl_xor(mx[r], off, 64));
#pragma unroll
        for (int f = 0; f < 13; f++) {
            bool val = (f * 16 + c1 < T_);
#pragma unroll
            for (int r = 0; r < 4; r++) {
                float e = val ? expf(acc[j][f][r] - mx[r]) : 0.f;
                acc[j][f][r] = e;
                sm[r] += e;
            }
        }
#pragma unroll
        for (int r = 0; r < 4; r++) {
#pragma unroll
            for (int off = 1; off < 16; off <<= 1) sm[r] += __shfl_xor(sm[r], off, 64);
            sm[r] = 1.f / sm[r];
        }
#pragma unroll
        for (int r = 0; r < 4; r++) {
            int qi = q0 + wv * 32 + j * 16 + grp * 4 + r;
            if (qi >= T_) continue;
            bf16* prow = Pm + ((long)z * T_ + qi) * TP_;
#pragma unroll
            for (int f = 0; f < 13; f++)
                prow[f * 16 + c1] = __float2bfloat16(acc[j][f][r] * sm[r]);
            prow[208 + c1] = z0;
        }
    }
}

// ---------------- GEMM kernels ----------------

__device__ __forceinline__ float geluf(float v) {
    return 0.5f * v * (1.f + erff(v * 0.70710678118654752f));
}

// C[M,N] = A[M,K] @ B[N,K]^T.  Guard-free loads. Compile-time K (KT), fully unrolled.
// Bank-conflict-free LDS swizzle (g^((row>>1)&3), both-sides involution).
// SWZ: bijective XCD chunk swizzle (m204).
// MODE 0: f32 (v+bias?)  1: bf16 (v+bias)  2: bf16 gelu(v+bias)  3: f32 (v+bias+res)
template<int MODE, bool GUARD, bool SWZ, int KT>
__global__ __launch_bounds__(256) void k_gemm_bt(
        const bf16* __restrict__ A, long lda, long bsA,
        const bf16* __restrict__ Bw, long ldb, long bsB,
        void* __restrict__ Cp, long ldc, long bsC,
        const float* __restrict__ bias,
        const float* res, long ldres,
        int Mt, int Nt) {
    __shared__ __align__(16) bf16 As[128][32];
    __shared__ __align__(16) bf16 Bs[128][32];
    int bz = blockIdx.z;
    A  += (long)bz * bsA;
    Bw += (long)bz * bsB;

    unsigned bx = blockIdx.x, by = blockIdx.y;
    if (SWZ) {
        unsigned nx = gridDim.x;
        unsigned nwg = nx * gridDim.y;
        unsigned f = by * nx + bx;
        unsigned q = nwg >> 3, r = nwg & 7;
        unsigned xcd = f & 7, idx = f >> 3;
        unsigned base = (xcd < r) ? xcd * (q + 1) : r * (q + 1) + (xcd - r) * q;
        unsigned nf = base + idx;
        bx = nf % nx;
        by = nf / nx;
    }
    int m0 = by * 128, n0 = bx * 128;

    int tid = threadIdx.x;
    int wv = tid >> 6, lane = tid & 63;
    int wm = (wv >> 1) * 64, wn = (wv & 1) * 64;
    int lrow = lane & 15, kgrp = lane >> 4;

    int rA = tid >> 2;
    int pA = (((tid & 3) ^ ((tid >> 3) & 3))) * 8;     // inverse-swizzled source col
    const bf16* gA0 = A  + (long)(m0 + rA) * lda + pA;
    const bf16* gA1 = A  + (long)(m0 + 64 + rA) * lda + pA;
    const bf16* gB0 = Bw + (long)(n0 + rA) * ldb + pA;
    const bf16* gB1 = Bw + (long)(n0 + 64 + rA) * ldb + pA;
    char* lA0 = (char*)As + (wv * 64) * 16;
    char* lA1 = (char*)As + (256 + wv * 64) * 16;
    char* lB0 = (char*)Bs + (wv * 64) * 16;
    char* lB1 = (char*)Bs + (256 + wv * 64) * 16;

    f32x4 acc[4][4];
#pragma unroll
    for (int i = 0; i < 4; i++)
#pragma unroll
        for (int j = 0; j < 4; j++) acc[i][j] = (f32x4){0.f, 0.f, 0.f, 0.f};

#pragma unroll
    for (int kt = 0; kt < (KT >> 5); kt++) {
        const long k0 = (long)kt << 5;
        gload16(gA0 + k0, lA0);
        gload16(gA1 + k0, lA1);
        gload16(gB0 + k0, lB0);
        gload16(gB1 + k0, lB1);
        __syncthreads();
        bf16x8 af[4], bfr[4];
#pragma unroll
        for (int mi = 0; mi < 4; mi++) {
            int R = wm + mi * 16 + lrow;
            af[mi] = *(const bf16x8*)&As[R][(kgrp ^ ((R >> 1) & 3)) * 8];
        }
#pragma unroll
        for (int ni = 0; ni < 4; ni++) {
            int R = wn + ni * 16 + lrow;
            bfr[ni] = *(const bf16x8*)&Bs[R][(kgrp ^ ((R >> 1) & 3)) * 8];
        }
#pragma unroll
        for (int mi = 0; mi < 4; mi++)
#pragma unroll
            for (int ni = 0; ni < 4; ni++)
                acc[mi][ni] = __builtin_amdgcn_mfma_f32_16x16x32_bf16(af[mi], bfr[ni], acc[mi][ni], 0, 0, 0);
        __syncthreads();
    }

    int r4 = (lane >> 4) * 4, c1 = lane & 15;
    float bv[4];
#pragma unroll
    for (int ni = 0; ni < 4; ni++) {
        int col = n0 + wn + ni * 16 + c1;
        bv[ni] = (bias && (!GUARD || col < Nt)) ? bias[col] : 0.f;
    }
#pragma unroll
    for (int mi = 0; mi < 4; mi++) {
#pragma unroll
        for (int r = 0; r < 4; r++) {
            int row = m0 + wm + mi * 16 + r4 + r;
            if (GUARD && row >= Mt) continue;
            long base = (long)bz * bsC + (long)row * ldc + n0 + wn + c1;
#pragma unroll
            for (int ni = 0; ni < 4; ni++) {
                if (GUARD && (n0 + wn + ni * 16 + c1) >= Nt) continue;
                float v = acc[mi][ni][r] + bv[ni];
                long cidx = base + ni * 16;
                if (MODE == 0)      ((float*)Cp)[cidx] = v;
                else if (MODE == 1) ((bf16*)Cp)[cidx]  = __float2bfloat16(v);
                else if (MODE == 2) ((bf16*)Cp)[cidx]  = __float2bfloat16(geluf(v));
                else                ((float*)Cp)[cidx] = v + res[(long)row * ldres + n0 + wn + c1 + ni * 16];
            }
        }
    }
}

// R = map_pair @ P (both heads, one launch). z: img=z&127, h2=z>>7.
__global__ __launch_bounds__(256) void k_gemm_r(
        const bf16* __restrict__ mapPair,      // [2][T][TP_]
        const bf16* __restrict__ Pb,           // [256][T][TP_]
        bf16* __restrict__ Rcat) {             // [128][224][448]
    __shared__ __align__(16) bf16 As[128][32];
    __shared__ __align__(16) bf16 Bs[128][32];
    int z = blockIdx.z;
    int img = z & 127, h2 = z >> 7;
    const bf16* A  = mapPair + (long)h2 * T_ * TP_;
    const bf16* Bw = Pb + ((long)(h2 * 128 + img)) * (long)T_ * TP_;
    bf16* Cp = Rcat + (long)img * 224 * RCW_ + h2 * 224;
    int m0 = blockIdx.y * 128, n0 = blockIdx.x * 128;
    int tid = threadIdx.x;
    int wv = tid >> 6, lane = tid & 63;
    int wm = (wv >> 1) * 64, wn = (wv & 1) * 64;
    int lrow = lane & 15, koff = (lane >> 4) * 8;

    int rA = tid >> 2, pA = (tid & 3) * 8;
    const bf16* gA0 = A + (long)(m0 + rA) * TP_ + pA;
    const bf16* gA1 = A + (long)(m0 + 64 + rA) * TP_ + pA;
    char* lA0 = (char*)As + (wv * 64) * 16;
    char* lA1 = (char*)As + (256 + wv * 64) * 16;
    int bk = tid & 31, bg = tid >> 5;

    f32x4 acc[4][4];
#pragma unroll
    for (int i = 0; i < 4; i++)
#pragma unroll
        for (int j = 0; j < 4; j++) acc[i][j] = (f32x4){0.f, 0.f, 0.f, 0.f};

#pragma unroll
    for (int kt = 0; kt < 7; kt++) {
        long k0 = (long)kt << 5;
        gload16(gA0 + k0, lA0);
        gload16(gA1 + k0, lA1);
#pragma unroll
        for (int i = 0; i < 2; i++) {
            int g = bg + 8 * i;
            uint4 v = *(const uint4*)(Bw + (k0 + bk) * TP_ + n0 + g * 8);
            const bf16* pv = (const bf16*)&v;
#pragma unroll
            for (int j = 0; j < 8; j++) Bs[g * 8 + j][bk] = pv[j];
        }
        __syncthreads();
        bf16x8 af[4], bfr[4];
#pragma unroll
        for (int mi = 0; mi < 4; mi++) af[mi]  = *(const bf16x8*)&As[wm + mi * 16 + lrow][koff];
#pragma unroll
        for (int ni = 0; ni < 4; ni++) bfr[ni] = *(const bf16x8*)&Bs[wn + ni * 16 + lrow][koff];
#pragma unroll
        for (int mi = 0; mi < 4; mi++)
#pragma unroll
            for (int ni = 0; ni < 4; ni++)
                acc[mi][ni] = __builtin_amdgcn_mfma_f32_16x16x32_bf16(af[mi], bfr[ni], acc[mi][ni], 0, 0, 0);
        __syncthreads();
    }

    int r4 = (lane >> 4) * 4, c1 = lane & 15;
#pragma unroll
    for (int mi = 0; mi < 4; mi++) {
#pragma unroll
        for (int r = 0; r < 4; r++) {
            int row = m0 + wm + mi * 16 + r4 + r;
            if (row >= T_) continue;
#pragma unroll
            for (int ni = 0; ni < 4; ni++) {
                int col = n0 + wn + ni * 16 + c1;
                if (col >= 224) continue;
                Cp[(long)row * RCW_ + col] = __float2bfloat16(acc[mi][ni][r]);
            }
        }
    }
}

// x += Rcat @ [V0;V1] (K=448 concat) + optional rowbias. z = img.
__global__ __launch_bounds__(256) void k_gemm_rv(
        const bf16* __restrict__ Rcat,         // [128][224][448]
        const bf16* __restrict__ ZV,           // [BT][2048]; V0 at +512, V1 at +1536
        float* __restrict__ xf,
        const float* __restrict__ rowbias) {
    __shared__ __align__(16) bf16 As[128][32];
    __shared__ __align__(16) bf16 Bs[128][32];
    int img = blockIdx.z;
    const bf16* A = Rcat + (long)img * 224 * RCW_;
    const bf16* Vimg = ZV + (long)img * T_ * ZVW2_;
    float* Cp = xf + (long)img * T_ * D_;
    int m0 = blockIdx.y * 128, n0 = blockIdx.x * 128;
    int tid = threadIdx.x;
    int wv = tid >> 6, lane = tid & 63;
    int wm = (wv >> 1) * 64, wn = (wv & 1) * 64;
    int lrow = lane & 15, koff = (lane >> 4) * 8;

    int rA = tid >> 2, pA = (tid & 3) * 8;
    const bf16* gA0 = A + (long)(m0 + rA) * RCW_ + pA;
    const bf16* gA1 = A + (long)(m0 + 64 + rA) * RCW_ + pA;
    char* lA0 = (char*)As + (wv * 64) * 16;
    char* lA1 = (char*)As + (256 + wv * 64) * 16;
    int bk = tid & 31, bg = tid >> 5;

    f32x4 acc[4][4];
#pragma unroll
    for (int i = 0; i < 4; i++)
#pragma unroll
        for (int j = 0; j < 4; j++) acc[i][j] = (f32x4){0.f, 0.f, 0.f, 0.f};

#pragma unroll
    for (int kt = 0; kt < 14; kt++) {
        long k0 = (long)kt << 5;
        gload16(gA0 + k0, lA0);
        gload16(gA1 + k0, lA1);
        const bf16* Vb = (kt < 7) ? (Vimg + 512 + k0 * ZVW2_)
                                  : (Vimg + 1536 + (k0 - 224) * ZVW2_);
#pragma unroll
        for (int i = 0; i < 2; i++) {
            int g = bg + 8 * i;
            uint4 v = *(const uint4*)(Vb + (long)bk * ZVW2_ + n0 + g * 8);
            const bf16* pv = (const bf16*)&v;
#pragma unroll
            for (int j = 0; j < 8; j++) Bs[g * 8 + j][bk] = pv[j];
        }
        __syncthreads();
        bf16x8 af[4], bfr[4];
#pragma unroll
        for (int mi = 0; mi < 4; mi++) af[mi]  = *(const bf16x8*)&As[wm + mi * 16 + lrow][koff];
#pragma unroll
        for (int ni = 0; ni < 4; ni++) bfr[ni] = *(const bf16x8*)&Bs[wn + ni * 16 + lrow][koff];
#pragma unroll
        for (int mi = 0; mi < 4; mi++)
#pragma unroll
            for (int ni = 0; ni < 4; ni++)
                acc[mi][ni] = __builtin_amdgcn_mfma_f32_16x16x32_bf16(af[mi], bfr[ni], acc[mi][ni], 0, 0, 0);
        __syncthreads();
    }

    int r4 = (lane >> 4) * 4, c1 = lane & 15;
#pragma unroll
    for (int mi = 0; mi < 4; mi++) {
#pragma unroll
        for (int r = 0; r < 4; r++) {
            int row = m0 + wm + mi * 16 + r4 + r;
            if (row >= T_) continue;
            float rb = rowbias ? rowbias[row] : 0.f;
#pragma unroll
            for (int ni = 0; ni < 4; ni++) {
                int col = n0 + wn + ni * 16 + c1;
                Cp[(long)row * D_ + col] += acc[mi][ni][r] + rb * 0.25f;
            }
        }
    }
}

// C[M,N] = A^T @ B. A [K][M], B [K][N] row-major, bf16 store. K%32==0.
__global__ __launch_bounds__(256) void k_gemm_tn(
        const bf16* __restrict__ A, long lda, long bsA,
        const bf16* __restrict__ Bw, long ldb, long bsB,
        bf16* __restrict__ Cp, long ldc, long bsC,
        int Mt, int Nt, int Kt) {
    __shared__ __align__(16) bf16 As[128][32];
    __shared__ __align__(16) bf16 Bs[128][32];
    int bz = blockIdx.z;
    A  += (long)bz * bsA;
    Bw += (long)bz * bsB;
    int m0 = blockIdx.y * 128, n0 = blockIdx.x * 128;
    int tid = threadIdx.x;
    int wv = tid >> 6, lane = tid & 63;
    int wm = (wv >> 1) * 64, wn = (wv & 1) * 64;
    int lrow = lane & 15, koff = (lane >> 4) * 8;
    int bk = tid & 31, bg = tid >> 5;

    f32x4 acc[4][4];
#pragma unroll
    for (int i = 0; i < 4; i++)
#pragma unroll
        for (int j = 0; j < 4; j++) acc[i][j] = (f32x4){0.f, 0.f, 0.f, 0.f};

    int kTiles = Kt >> 5;
    for (int kt = 0; kt < kTiles; kt++) {
        long k0 = (long)kt << 5;
#pragma unroll
        for (int i = 0; i < 2; i++) {
            int g = bg + 8 * i;
            uint4 va = *(const uint4*)(A + (k0 + bk) * lda + m0 + g * 8);
            const bf16* pa = (const bf16*)&va;
#pragma unroll
            for (int j = 0; j < 8; j++) As[g * 8 + j][bk] = pa[j];
            uint4 vb = *(const uint4*)(Bw + (k0 + bk) * ldb + n0 + g * 8);
            const bf16* pb = (const bf16*)&vb;
#pragma unroll
            for (int j = 0; j < 8; j++) Bs[g * 8 + j][bk] = pb[j];
        }
        __syncthreads();
        bf16x8 af[4], bfr[4];
#pragma unroll
        for (int mi = 0; mi < 4; mi++) af[mi]  = *(const bf16x8*)&As[wm + mi * 16 + lrow][koff];
#pragma unroll
        for (int ni = 0; ni < 4; ni++) bfr[ni] = *(const bf16x8*)&Bs[wn + ni * 16 + lrow][koff];
#pragma unroll
        for (int mi = 0; mi < 4; mi++)
#pragma unroll
            for (int ni = 0; ni < 4; ni++)
                acc[mi][ni] = __builtin_amdgcn_mfma_f32_16x16x32_bf16(af[mi], bfr[ni], acc[mi][ni], 0, 0, 0);
        __syncthreads();
    }

    int r4 = (lane >> 4) * 4, c1 = lane & 15;
#pragma unroll
    for (int mi = 0; mi < 4; mi++) {
#pragma unroll
        for (int r = 0; r < 4; r++) {
            int row = m0 + wm + mi * 16 + r4 + r;
            if (row >= Mt) continue;
#pragma unroll
            for (int ni = 0; ni < 4; ni++) {
                int col = n0 + wn + ni * 16 + c1;
                if (col >= Nt) continue;
                Cp[(long)bz * bsC + (long)row * ldc + col] = __float2bfloat16(acc[mi][ni][r]);
            }
        }
    }
}

// ---------------- classifier + softmax ----------------

__global__ __launch_bounds__(64) void k_classifier(const float* __restrict__ x,
        const float* __restrict__ w, const float* __restrict__ bias, float* __restrict__ out) {
    int b = blockIdx.x, lane = threadIdx.x;
    const float* xr = x + (long)b * T_ * D_;
    float logits[NC_];
#pragma unroll
    for (int c = 0; c < NC_; c++) {
        float s = 0.f;
        for (int d = lane; d < D_; d += 64) s += xr[d] * w[c * D_ + d];
#pragma unroll
        for (int off = 32; off; off >>= 1) s += __shfl_xor(s, off, 64);
        logits[c] = s + bias[c];
    }
    float mx = -1e30f;
#pragma unroll
    for (int c = 0; c < NC_; c++) mx = fmaxf(mx, logits[c]);
    float sum = 0.f;
#pragma unroll
    for (int c = 0; c < NC_; c++) { float e = expf(logits[c] - mx); logits[c] = e; sum += e; }
    if (lane == 0) {
        float inv = 1.f / sum;
#pragma unroll
        for (int c = 0; c < NC_; c++) out[(long)b * NC_ + c] = logits[c] * inv;
    }
}

// ---------------- host ----------------

extern "C" void kernel_launch(void* const* d_in, const int* in_sizes, int n_in,
                              void* d_out, int out_size, void* d_ws, size_t ws_size,
                              hipStream_t stream) {
    const float* images  = (const float*)d_in[0];
    const float* lin_w   = (const float*)d_in[1];
    const float* lin_b   = (const float*)d_in[2];
    const float* cls_tok = (const float*)d_in[3];
    const float* ln1_g   = (const float*)d_in[4];
    const float* ln1_b   = (const float*)d_in[5];
    const float* ln2_g   = (const float*)d_in[6];
    const float* ln2_b   = (const float*)d_in[7];
    const float* qw      = (const float*)d_in[8];
    const float* qb      = (const float*)d_in[9];
    const float* kw      = (const float*)d_in[10];
    const float* kb      = (const float*)d_in[11];
    const float* vw      = (const float*)d_in[12];
    const float* vb      = (const float*)d_in[13];
    const float* map_w   = (const float*)d_in[14];
    const float* map_b   = (const float*)d_in[15];
    const float* w1      = (const float*)d_in[16];
    const float* b1      = (const float*)d_in[17];
    const float* w2      = (const float*)d_in[18];
    const float* b2      = (const float*)d_in[19];
    const float* cls_w   = (const float*)d_in[20];
    const float* cls_b   = (const float*)d_in[21];

    char* wp = (char*)d_ws;
    auto alloc = [&](size_t bytes) { char* p = wp; wp += (bytes + 255) & ~(size_t)255; return p; };
    const long BT = (long)B_ * T_;                       // 25216 = 197*128 exactly

    // ~244 MB total. Pads absorb guard-free tile overreads (finite poison).
    float* xf   = (float*)alloc(BT * D_ * 4);
    bf16*  hb   = (bf16*) alloc((BT + 192) * D_ * 2);
    bf16*  ZVh2 = (bf16*) alloc((size_t)(BT + 160) * ZVW2_ * 2);    // 2-head Z|V ∪ m1 (MLP)
    bf16*  m1c  = ZVh2;
    bf16*  Pb2  = (bf16*) alloc(((size_t)256 * T_ + 64) * TP_ * 2); // both heads' P
    char*  rcReg= alloc(((size_t)128 * 224 + 64) * RCW_ * 2);       // Rcat ∪ patches ∪ wqb/wkb
    bf16*  Rcat = (bf16*)rcReg;
    bf16*  patches = (bf16*)rcReg;
    bf16*  wqb  = (bf16*)rcReg;
    bf16*  wkb  = (bf16*)(rcReg + (long)NH_ * D_ * D_ * 2);
    bf16*  wzv  = (bf16*) alloc(((long)NH_ * 1024 + 64) * D_ * 2);
    float* zvb  = (float*)alloc((long)NH_ * 1024 * 4);
    bf16*  wmapP= (bf16*) alloc(((long)NH_ * T_ + 64) * TP_ * 2);
    bf16*  w1l  = (bf16*) alloc((long)(M_ + 64) * D_ * 2);
    bf16*  w2l  = (bf16*) alloc((long)(D_ + 64) * M_ * 2);
    bf16*  wlin = (bf16*) alloc((long)(D_ + 64) * 256 * 2);

    k_f32_to_bf16v<<<1024, 256, 0, stream>>>(lin_w, wlin, (long)D_ * 256 / 8);
    {
        long tot = (long)B_ * 196 * 256;
        k_patchify<<<(int)((tot + 255) / 256), 256, 0, stream>>>(images, patches);
        k_cls_token<<<(B_ * D_ + 255) / 256, 256, 0, stream>>>(cls_tok, xf);
        k_gemm_bt<0, true, false, 256><<<dim3(4, 2, B_), 256, 0, stream>>>(
            patches, 256, (long)196 * 256,
            wlin, 256, 0,
            xf + D_, D_, (long)T_ * D_,
            lin_b, nullptr, 0,
            196, D_);
    }

    const float scale = 1.0f / 14.0f;
    const int lnGrid = (int)((BT + 3) / 4);

    for (int l = 0; l < L_; l++) {
        // ---- per-layer weight prep (merged conversions) ----
        k_f32_to_bf16v4<<<1024, 256, 0, stream>>>(
            qw + (long)l * NH_ * D_ * D_, wqb,
            kw + (long)l * NH_ * D_ * D_, wkb, (long)NH_ * D_ * D_ / 8,
            w1 + (long)l * M_ * D_, w1l,
            w2 + (long)l * D_ * M_, w2l, (long)M_ * D_ / 8);
        k_gemm_tn<<<dim3(4, 4, NH_), 256, 0, stream>>>(
            wkb, D_, (long)D_ * D_,
            wqb, D_, (long)D_ * D_,
            wzv, D_, (long)1024 * D_,
            D_, D_, D_);
        k_prep_wv<<<(NH_ * D_ * (D_ / 8) + 255) / 256, 256, 0, stream>>>(
            vw + (long)l * NH_ * D_ * D_, wzv);
        k_prep_ub<<<(NH_ * 512 + NH_ * 8 + 3) / 4, 256, 0, stream>>>(
            kw + (long)l * NH_ * D_ * D_, qb + (long)l * NH_ * D_,
            vb + (long)l * NH_ * D_, zvb);
        k_prep_map<<<(NH_ * T_ * TP_ + 255) / 256, 256, 0, stream>>>(
            map_w + (long)l * T_ * T_ * NH_, wmapP);

        k_ln<0><<<lnGrid, 256, 0, stream>>>(xf, ln1_g + l * D_, ln1_b + l * D_, hb, nullptr, (int)BT);

        for (int hp = 0; hp < 4; hp++) {
            // fused 2-head [Z0|V0|Z1|V1] = hb @ Wpair^T + bias (N=2048), XCD-swizzled
            k_gemm_bt<1, false, true, 512><<<dim3(16, 197, 1), 256, 0, stream>>>(
                hb, D_, 0, wzv + (long)hp * 2048 * D_, D_, 0,
                ZVh2, ZVW2_, 0, zvb + (long)hp * 2048, nullptr, 0,
                (int)BT, ZVW2_);

            // P for both heads: z = h2*128 + img
            k_attn_ssm2<<<dim3(1, 2, 256), 256, 0, stream>>>(
                ZVh2, ZVW2_, (long)T_ * ZVW2_, 1024,
                hb, D_, (long)T_ * D_,
                Pb2, scale);

            // Rcat = [map_h0 @ P_h0 | map_h1 @ P_h1]  (one launch, both heads)
            k_gemm_r<<<dim3(2, 2, 256), 256, 0, stream>>>(
                wmapP + (long)(hp * 2) * T_ * TP_, Pb2, Rcat);

            // x += Rcat @ [V0;V1]  (K=448; map_b rowbias spread over 4 pair-launches)
            k_gemm_rv<<<dim3(4, 2, B_), 256, 0, stream>>>(
                Rcat, ZVh2, xf, map_b + (long)l * T_);
        }

        // y = LN2(x): bf16 -> hb, f32 in-place over xf
        k_ln<1><<<lnGrid, 256, 0, stream>>>(xf, ln2_g + l * D_, ln2_b + l * D_, hb, xf, (int)BT);

        // MLP full-batch, exact-shape, XCD-swizzled
        k_gemm_bt<2, false, true, 512><<<dim3(16, 197, 1), 256, 0, stream>>>(
            hb, D_, 0, w1l, D_, 0,
            m1c, M_, 0, b1 + (long)l * M_, nullptr, 0, (int)BT, M_);
        k_gemm_bt<3, false, true, 2048><<<dim3(4, 197, 1), 256, 0, stream>>>(
            m1c, M_, 0, w2l, M_, 0,
            xf, D_, 0, b2 + (long)l * D_, xf, D_, (int)BT, D_);
    }

    k_classifier<<<B_, 64, 0, stream>>>(xf, cls_w, cls_b, (float*)d_out);
}